// Round 2
// baseline (117.065 us; speedup 1.0000x reference)
//
#include <hip/hip_runtime.h>
#include <math.h>

// DAS beamforming: out[b][c][p] = sum_s data[b][c][s][t(s,p)]
// Table chain: ONLY the f64-emulated chain is proven bit-exact (r5/r6/r8
// absmax 0.0). r7's native-f32 version regressed (3.56). DO NOT change it.
// r10: 8ch packed bf16 in one 16B slot. absmax 0.25 (bf16 quant, inside 1.08).
// r11: LDS-staged windows (tmin monotone lower bound, span<=56). 49.5us --
//   SLOWER than r10 gather (<43us): occupancy 17% (2 blk/CU) + 3 serialized
//   LDS round-trips per sensor = latency-bound (VALUBusy 48%, HBM 5%).
// r12 (this round): ILP phase-split. Per chunk: issue ALL 32 ds_read_u16
//   t-lookups into regs, then ALL 32 ds_read_b128 window reads + adds.
//   tmin pre-subtracted into staged patch (kills per-sensor meta.w dep);
//   per-sensor meta = one b64 broadcast; ls*stride folded to offset: imm.
//   Same values, same s-ascending order -> bit-identical to r11.

#define NXY 512
#define S_CNT 128
#define T_CNT 2048
#define CH 8                       // B*2 = 4*2
#define CH_STRIDE (S_CNT * T_CNT)  // 262144 floats between channels (orig layout)
#define NPIX (NXY * NXY)
#define TAB_BYTES (NPIX * 2)       // 512 KB u16 table
#define CHUNK 32                   // sensors staged per LDS pass
#define NCHUNK (S_CNT / CHUNK)
#define WIN 64                     // d2b window entries per sensor (span <= 56)
#define PATW 24                    // staged table patch width (u16)
#define PAT_STRIDE (16 * PATW)     // 384 u16 per sensor patch

#pragma float_control(push)
#pragma float_control(precise, on)
__device__ __forceinline__ unsigned short delay_entry(int adx, int ady) {
    const double DX32 = (double)1e-4f;                        // f32 const, exact widen
    const double R1 = (double)(float)(1.0 / 1550.0);          // CR f32 reciprocal
    const double R2 = (double)(float)(1.0 / (double)2.5e-8f); // = 4.0e7 exactly
    float dxf = (float)((double)adx * DX32);        // exact f64 product -> f32 round
    float dyf = (float)((double)ady * DX32);
    float a2 = (float)((double)dxf * (double)dxf);  // exact in f64 -> f32 round
    float b2 = (float)((double)dyf * (double)dyf);
    float sum = (float)((double)a2 + (double)b2);   // exact in f64 -> f32 round
    float dis = (float)sqrt((double)sum);           // CR f32 sqrt
    float q1 = (float)((double)dis * R1);           // CR f32 mul
    float q2 = (float)((double)q1 * R2);            // CR f32 mul
    return (unsigned short)(int)q2;                 // trunc; max 1864
}

__device__ __forceinline__ unsigned int bf16_rne(float f) {
    unsigned int x = __float_as_uint(f);
    return (x + 0x7fffu + ((x >> 16) & 1u)) >> 16;  // round-to-nearest-even
}

// Fused, x4 vectorized: table + transpose-convert (8ch,128s,2048t)f32 ->
// (128s,2048t)x(8ch bf16 in 16B). 256 blocks x 256 thr, 4 pixels/thread.
__global__ __launch_bounds__(256) void prep4(const float* __restrict__ data,
                                             unsigned short* __restrict__ tab,
                                             uint4* __restrict__ d2b) {
    int g = blockIdx.x * 256 + threadIdx.x;  // 0..65535, pixels 4g..4g+3
    unsigned int t01, t23;
    {
        int i0 = 4 * g;
        t01 = (unsigned int)delay_entry(i0 >> 9, i0 & 511) |
              ((unsigned int)delay_entry((i0 + 1) >> 9, (i0 + 1) & 511) << 16);
        t23 = (unsigned int)delay_entry((i0 + 2) >> 9, (i0 + 2) & 511) |
              ((unsigned int)delay_entry((i0 + 3) >> 9, (i0 + 3) & 511) << 16);
    }
    ((uint2*)tab)[g] = make_uint2(t01, t23);

    const float4* data4 = (const float4*)data;
    float4 v[CH];
#pragma unroll
    for (int ch = 0; ch < CH; ++ch) v[ch] = data4[ch * (CH_STRIDE / 4) + g];
#pragma unroll
    for (int q = 0; q < 4; ++q) {
        const float* e0 = (const float*)&v[0];
        unsigned int w0 = bf16_rne(((const float*)&v[0])[q]) | (bf16_rne(((const float*)&v[1])[q]) << 16);
        unsigned int w1 = bf16_rne(((const float*)&v[2])[q]) | (bf16_rne(((const float*)&v[3])[q]) << 16);
        unsigned int w2 = bf16_rne(((const float*)&v[4])[q]) | (bf16_rne(((const float*)&v[5])[q]) << 16);
        unsigned int w3 = bf16_rne(((const float*)&v[6])[q]) | (bf16_rne(((const float*)&v[7])[q]) << 16);
        d2b[4 * g + q] = make_uint4(w0, w1, w2, w3);
        (void)e0;
    }
}

// meta helper must carry precise semantics
__device__ __forceinline__ int tmin_entry(int adx, int ady) {
    return (int)delay_entry(adx, ady);
}
#pragma float_control(pop)

__device__ __forceinline__ float bflo(unsigned int u) { return __uint_as_float(u << 16); }
__device__ __forceinline__ float bfhi(unsigned int u) { return __uint_as_float(u & 0xffff0000u); }

// per-halfword (a - t) mod 2^16; used entries land in [0,56]
__device__ __forceinline__ unsigned int sub16x2(unsigned int a, unsigned int t) {
    unsigned int lo = (a - t) & 0xffffu;
    unsigned int hi = ((a >> 16) - t) << 16;
    return lo | hi;
}

// Gather v3: LDS windows + ILP phase-split. Wave = 8x8 px tile, block 16x16 (4 waves).
__global__ __launch_bounds__(256) void das_gather_ilp(const uint4* __restrict__ d2b,
                                                      const unsigned short* __restrict__ tab,
                                                      const int* __restrict__ sxy,
                                                      float* __restrict__ out) {
    __shared__ uint2 minfo[S_CNT];         // inner:  sx|sy<<16, ax0*24+ay0
    __shared__ uint2 mstage[S_CNT];        // staging: ax0|ay0<<16, tmin
    __shared__ uint4 winb[CHUNK * WIN];    // d2b windows, 32 KB
    __shared__ uint4 patb[CHUNK * 16 * 3]; // patches (tab - tmin), 16 x 24 u16, 24 KB
    const unsigned short* pat16 = (const unsigned short*)patb;

    int tid = threadIdx.x;
    int x0 = (blockIdx.x >> 5) << 4;  // tile origin
    int y0 = (blockIdx.x & 31) << 4;

    if (tid < S_CNT) {
        int sxv = sxy[2 * tid];
        int syv = sxy[2 * tid + 1];
        int axm = sxv < x0 ? x0 - sxv : (sxv > x0 + 15 ? sxv - x0 - 15 : 0);
        int aym = syv < y0 ? y0 - syv : (syv > y0 + 15 ? syv - y0 - 15 : 0);
        int ay0 = aym & ~7;                  // 16B-align patch column start
        int tmin = tmin_entry(axm, aym);     // exact monotone lower bound
        minfo[tid] = make_uint2((unsigned int)(sxv | (syv << 16)),
                                (unsigned int)(axm * PATW + ay0));
        mstage[tid] = make_uint2((unsigned int)(axm | (ay0 << 16)), (unsigned int)tmin);
    }
    __syncthreads();

    // lane bits: iy[2:0]=tid[2:0], ix[2:0]=tid[5:3]; wave bits: iy[3]=tid[6], ix[3]=tid[7]
    int iy = y0 | (((tid >> 6) & 1) << 3) | (tid & 7);
    int ix = x0 | ((tid >> 7) << 3) | ((tid >> 3) & 7);

    float acc[CH];
#pragma unroll
    for (int k = 0; k < CH; ++k) acc[k] = 0.0f;

    for (int c = 0; c < NCHUNK; ++c) {
        int s0 = c * CHUNK;

        // --- stage d2b windows: 32 sensors x 64 x 16B = 32 KB, 8 uint4/thread.
        {
            int lsw = tid >> 3;  // local sensor 0..31
            int tm = (int)mstage[s0 + lsw].y;
            const uint4* src = d2b + ((s0 + lsw) << 11) + tm;
            int e0 = tid & 7;
#pragma unroll
            for (int j = 0; j < 8; ++j)
                winb[(lsw << 6) + e0 + 8 * j] = src[e0 + 8 * j];
        }

        // --- stage patches minus tmin: 32 x 16 rows x 3 uint4 = 24 KB, 6/thread.
        // Worst case reads 16B past table end (into d2b base) - staged, unused.
#pragma unroll
        for (int j = 0; j < 6; ++j) {
            unsigned int idx = (unsigned int)tid + 256u * j;  // 0..1535
            unsigned int r3 = idx / 3u;                       // magic mul
            unsigned int cc = idx - r3 * 3u;
            unsigned int row = r3 & 15u;
            unsigned int ls = r3 >> 4;
            uint2 st = mstage[s0 + ls];
            int ax0 = (int)(st.x & 0xffffu);
            int ay0 = (int)(st.x >> 16);
            unsigned int tm = st.y;
            const uint4* src = (const uint4*)((const char*)tab +
                (((size_t)(ax0 + (int)row) << 10) + ((size_t)ay0 << 1) + ((size_t)cc << 4)));
            uint4 v = *src;
            v.x = sub16x2(v.x, tm);
            v.y = sub16x2(v.y, tm);
            v.z = sub16x2(v.z, tm);
            v.w = sub16x2(v.w, tm);
            patb[ls * 48u + row * 3u + cc] = v;
        }
        __syncthreads();

        // --- t-phase: 32 independent ds_read_u16 into regs (ILP)
        unsigned int tw[CHUNK];
#pragma unroll
        for (int ls = 0; ls < CHUNK; ++ls) {
            uint2 mi = minfo[s0 + ls];  // b64 broadcast
            int sxv = (int)(mi.x & 0xffffu);
            int syv = (int)(mi.x >> 16);
            int dxi = sxv - ix;
            int dyi = syv - iy;
            int adx = dxi < 0 ? -dxi : dxi;
            int ady = dyi < 0 ? -dyi : dyi;
            int pidx = adx * PATW + ady - (int)mi.y;  // in [0,384)
            tw[ls] = (unsigned int)pat16[ls * PAT_STRIDE + pidx];  // t - tmin, <= 56
        }

        // --- w-phase: 32 independent ds_read_b128 + accumulate (s-ascending)
#pragma unroll
        for (int ls = 0; ls < CHUNK; ++ls) {
            uint4 w = winb[(ls << 6) + tw[ls]];
            acc[0] += bflo(w.x);
            acc[1] += bfhi(w.x);
            acc[2] += bflo(w.y);
            acc[3] += bfhi(w.y);
            acc[4] += bflo(w.z);
            acc[5] += bfhi(w.z);
            acc[6] += bflo(w.w);
            acc[7] += bfhi(w.w);
        }
        __syncthreads();  // protect LDS before next chunk's staging
    }

    int pix = (ix << 9) | iy;
#pragma unroll
    for (int k = 0; k < CH; ++k) out[k * NPIX + pix] = acc[k];
}

// ---------- fallback path (ws too small): r5-proven build_table + das_main ----------
#pragma float_control(push)
#pragma float_control(precise, on)
__global__ __launch_bounds__(256) void build_table(unsigned short* __restrict__ tab) {
    int idx = blockIdx.x * 256 + threadIdx.x;
    tab[idx] = delay_entry(idx >> 9, idx & 511);
}
#pragma float_control(pop)

__global__ __launch_bounds__(256) void das_main(const float* __restrict__ data,
                                                const unsigned short* __restrict__ tab,
                                                const int* __restrict__ sxy,
                                                float* __restrict__ out) {
    __shared__ int sx[S_CNT];
    __shared__ int sy[S_CNT];
    int tid = threadIdx.x;
    if (tid < S_CNT) {
        sx[tid] = sxy[2 * tid];
        sy[tid] = sxy[2 * tid + 1];
    }
    __syncthreads();
    int iy = ((blockIdx.x & 31) << 4) | (tid & 15);
    int ix = ((blockIdx.x >> 5) << 4) | (tid >> 4);
    float acc[CH];
#pragma unroll
    for (int k = 0; k < CH; ++k) acc[k] = 0.0f;
#pragma unroll 4
    for (int s = 0; s < S_CNT; ++s) {
        int dxi = sx[s] - ix;
        int dyi = sy[s] - iy;
        int adx = dxi < 0 ? -dxi : dxi;
        int ady = dyi < 0 ? -dyi : dyi;
        int t = (int)tab[(adx << 9) | ady];
        const float* p = data + (s << 11) + t;
#pragma unroll
        for (int k = 0; k < CH; ++k) acc[k] += p[(size_t)k * CH_STRIDE];
    }
    int pix = (ix << 9) | iy;
#pragma unroll
    for (int k = 0; k < CH; ++k) out[k * NPIX + pix] = acc[k];
}

extern "C" void kernel_launch(void* const* d_in, const int* in_sizes, int n_in,
                              void* d_out, int out_size, void* d_ws, size_t ws_size,
                              hipStream_t stream) {
    const float* data = (const float*)d_in[0];     // (4,2,128,2048) f32
    const int* sxy = (const int*)d_in[1];          // (128,2) i32
    float* out = (float*)d_out;                    // (4,2,512,512) f32
    unsigned short* tab = (unsigned short*)d_ws;   // 512 KB

    size_t need = (size_t)TAB_BYTES + (size_t)CH_STRIDE * 16;  // 512KB + 4MB
    if (ws_size >= need) {
        uint4* d2b = (uint4*)((char*)d_ws + TAB_BYTES);
        prep4<<<NPIX / 1024, 256, 0, stream>>>(data, tab, d2b);
        das_gather_ilp<<<1024, 256, 0, stream>>>(d2b, tab, sxy, out);
    } else {
        build_table<<<NPIX / 256, 256, 0, stream>>>(tab);
        das_main<<<1024, 256, 0, stream>>>(data, tab, sxy, out);
    }
}

// Round 3
// 101.195 us; speedup vs baseline: 1.1568x; 1.1568x over previous
//
#include <hip/hip_runtime.h>
#include <math.h>

// DAS beamforming: out[b][c][p] = sum_s data[b][c][s][t(s,p)]
// Table chain: ONLY the f64-emulated chain is proven bit-exact (r5/r6/r8
// absmax 0.0). r7's native-f32 version regressed (3.56). DO NOT change it.
// r10: 8ch packed bf16 in one 16B slot, VMEM gather: total 96.5, gather ~40.
// r11: LDS windows+patches: gather 49.5. SLOWER -- 59KB LDS -> 2 blk/CU,
//   latency-bound (VALUBusy 48%, HBM 5%).
// r12: ILP phase-split: gather 60.4. WORSE -- bulk LDS phases serialize on
//   lgkmcnt at 2 blk/CU; window staging is the structural mistake.
// r13 (this round): hybrid. Keep ONLY the tab->LDS patch staging (6 coalesced
//   dwordx4/thread/chunk, 24KB), read d2b DIRECTLY via VMEM like r10.
//   Per-thread VMEM 256 -> 152; tab lookup becomes ds_read_u16; 26KB LDS ->
//   6 blk/CU (24 waves). Same values, same s-ascending order as r10.

#define NXY 512
#define S_CNT 128
#define T_CNT 2048
#define CH 8                       // B*2 = 4*2
#define CH_STRIDE (S_CNT * T_CNT)  // 262144 floats between channels (orig layout)
#define NPIX (NXY * NXY)
#define TAB_BYTES (NPIX * 2)       // 512 KB u16 table
#define CHUNK 32                   // sensors per LDS patch pass
#define NCHUNK (S_CNT / CHUNK)
#define PATW 24                    // staged table patch width (u16), 16B-aligned rows
#define PAT_STRIDE (16 * PATW)     // 384 u16 per sensor patch

#pragma float_control(push)
#pragma float_control(precise, on)
__device__ __forceinline__ unsigned short delay_entry(int adx, int ady) {
    const double DX32 = (double)1e-4f;                        // f32 const, exact widen
    const double R1 = (double)(float)(1.0 / 1550.0);          // CR f32 reciprocal
    const double R2 = (double)(float)(1.0 / (double)2.5e-8f); // = 4.0e7 exactly
    float dxf = (float)((double)adx * DX32);        // exact f64 product -> f32 round
    float dyf = (float)((double)ady * DX32);
    float a2 = (float)((double)dxf * (double)dxf);  // exact in f64 -> f32 round
    float b2 = (float)((double)dyf * (double)dyf);  // exact in f64 -> f32 round
    float sum = (float)((double)a2 + (double)b2);   // exact in f64 -> f32 round
    float dis = (float)sqrt((double)sum);           // CR f32 sqrt
    float q1 = (float)((double)dis * R1);           // CR f32 mul
    float q2 = (float)((double)q1 * R2);            // CR f32 mul
    return (unsigned short)(int)q2;                 // trunc; max 1864
}

__device__ __forceinline__ unsigned int bf16_rne(float f) {
    unsigned int x = __float_as_uint(f);
    return (x + 0x7fffu + ((x >> 16) & 1u)) >> 16;  // round-to-nearest-even
}

// Fused, x4 vectorized: table + transpose-convert (8ch,128s,2048t)f32 ->
// (128s,2048t)x(8ch bf16 in 16B). 256 blocks x 256 thr, 4 pixels/thread.
__global__ __launch_bounds__(256) void prep4(const float* __restrict__ data,
                                             unsigned short* __restrict__ tab,
                                             uint4* __restrict__ d2b) {
    int g = blockIdx.x * 256 + threadIdx.x;  // 0..65535, pixels 4g..4g+3
    unsigned int t01, t23;
    {
        int i0 = 4 * g;
        t01 = (unsigned int)delay_entry(i0 >> 9, i0 & 511) |
              ((unsigned int)delay_entry((i0 + 1) >> 9, (i0 + 1) & 511) << 16);
        t23 = (unsigned int)delay_entry((i0 + 2) >> 9, (i0 + 2) & 511) |
              ((unsigned int)delay_entry((i0 + 3) >> 9, (i0 + 3) & 511) << 16);
    }
    ((uint2*)tab)[g] = make_uint2(t01, t23);

    const float4* data4 = (const float4*)data;
    float4 v[CH];
#pragma unroll
    for (int ch = 0; ch < CH; ++ch) v[ch] = data4[ch * (CH_STRIDE / 4) + g];
#pragma unroll
    for (int q = 0; q < 4; ++q) {
        unsigned int w0 = bf16_rne(((const float*)&v[0])[q]) | (bf16_rne(((const float*)&v[1])[q]) << 16);
        unsigned int w1 = bf16_rne(((const float*)&v[2])[q]) | (bf16_rne(((const float*)&v[3])[q]) << 16);
        unsigned int w2 = bf16_rne(((const float*)&v[4])[q]) | (bf16_rne(((const float*)&v[5])[q]) << 16);
        unsigned int w3 = bf16_rne(((const float*)&v[6])[q]) | (bf16_rne(((const float*)&v[7])[q]) << 16);
        d2b[4 * g + q] = make_uint4(w0, w1, w2, w3);
    }
}
#pragma float_control(pop)

__device__ __forceinline__ float bflo(unsigned int u) { return __uint_as_float(u << 16); }
__device__ __forceinline__ float bfhi(unsigned int u) { return __uint_as_float(u & 0xffff0000u); }

// Gather v4 (hybrid): tab patches in LDS, d2b gathered direct from L2.
// Wave = 8x8 px tile, block = 16x16 px (4 waves). 26 KB LDS -> 6 blocks/CU.
__global__ __launch_bounds__(256) void das_hybrid(const uint4* __restrict__ d2b,
                                                  const unsigned short* __restrict__ tab,
                                                  const int* __restrict__ sxy,
                                                  float* __restrict__ out) {
    __shared__ uint2 minfo[S_CNT];          // inner:   sx|sy<<16, ax0*24+ay0
    __shared__ unsigned int mstage[S_CNT];  // staging: ax0 | ay0<<16
    __shared__ uint4 patb[CHUNK * 16 * 3];  // raw tab patches, 16 x 24 u16, 24 KB
    const unsigned short* pat16 = (const unsigned short*)patb;

    int tid = threadIdx.x;
    int x0 = (blockIdx.x >> 5) << 4;  // tile origin
    int y0 = (blockIdx.x & 31) << 4;

    if (tid < S_CNT) {
        int sxv = sxy[2 * tid];
        int syv = sxy[2 * tid + 1];
        // component-wise min of |sx-ix|, |sy-iy| over the 16x16 tile
        int axm = sxv < x0 ? x0 - sxv : (sxv > x0 + 15 ? sxv - x0 - 15 : 0);
        int aym = syv < y0 ? y0 - syv : (syv > y0 + 15 ? syv - y0 - 15 : 0);
        int ay0 = aym & ~7;  // 16B-align patch row start
        minfo[tid] = make_uint2((unsigned int)(sxv | (syv << 16)),
                                (unsigned int)(axm * PATW + ay0));
        mstage[tid] = (unsigned int)(axm | (ay0 << 16));
    }
    __syncthreads();

    // lane bits: iy[2:0]=tid[2:0], ix[2:0]=tid[5:3]; wave bits: iy[3]=tid[6], ix[3]=tid[7]
    int iy = y0 | (((tid >> 6) & 1) << 3) | (tid & 7);
    int ix = x0 | ((tid >> 7) << 3) | ((tid >> 3) & 7);

    float acc[CH];
#pragma unroll
    for (int k = 0; k < CH; ++k) acc[k] = 0.0f;

    for (int c = 0; c < NCHUNK; ++c) {
        int s0 = c * CHUNK;

        // --- stage raw tab patches: 32 sensors x 16 rows x 3 uint4 = 24 KB,
        // 6 coalesced dwordx4 per thread. Rows 16B-aligned (ay0 even-8).
        // Worst case reads 16B past table end (into d2b base) - staged, unused.
#pragma unroll
        for (int j = 0; j < 6; ++j) {
            unsigned int idx = (unsigned int)tid + 256u * j;  // 0..1535
            unsigned int r3 = idx / 3u;                       // magic mul
            unsigned int cc = idx - r3 * 3u;
            unsigned int row = r3 & 15u;
            unsigned int ls = r3 >> 4;
            unsigned int st = mstage[s0 + ls];
            int ax0 = (int)(st & 0xffffu);
            int ay0 = (int)(st >> 16);
            const uint4* src = (const uint4*)((const char*)tab +
                (((size_t)(ax0 + (int)row) << 10) + ((size_t)ay0 << 1) + ((size_t)cc << 4)));
            patb[ls * 48u + row * 3u + cc] = *src;
        }
        __syncthreads();

        // --- inner: per sensor 1 ds_read_u16 (t) + 1 VMEM b128 (d2b) + 8 adds.
        // r10-proven chain shape; moderate unroll keeps several VMEM in flight.
#pragma unroll 4
        for (int ls = 0; ls < CHUNK; ++ls) {
            uint2 mi = minfo[s0 + ls];  // b64 broadcast (no conflict)
            int sxv = (int)(mi.x & 0xffffu);
            int syv = (int)(mi.x >> 16);
            int dxi = sxv - ix;
            int dyi = syv - iy;
            int adx = dxi < 0 ? -dxi : dxi;
            int ady = dyi < 0 ? -dyi : dyi;
            int pidx = adx * PATW + ady - (int)mi.y;               // in [0,384)
            int t = (int)pat16[ls * PAT_STRIDE + pidx];            // raw delay
            uint4 w = d2b[((s0 + ls) << 11) + t];                  // direct L2 gather
            acc[0] += bflo(w.x);  // per-channel s-ascending: deterministic
            acc[1] += bfhi(w.x);
            acc[2] += bflo(w.y);
            acc[3] += bfhi(w.y);
            acc[4] += bflo(w.z);
            acc[5] += bfhi(w.z);
            acc[6] += bflo(w.w);
            acc[7] += bfhi(w.w);
        }
        __syncthreads();  // protect patb before next chunk's staging
    }

    int pix = (ix << 9) | iy;
#pragma unroll
    for (int k = 0; k < CH; ++k) out[k * NPIX + pix] = acc[k];
}

// ---------- fallback path (ws too small): r5-proven build_table + das_main ----------
#pragma float_control(push)
#pragma float_control(precise, on)
__global__ __launch_bounds__(256) void build_table(unsigned short* __restrict__ tab) {
    int idx = blockIdx.x * 256 + threadIdx.x;
    tab[idx] = delay_entry(idx >> 9, idx & 511);
}
#pragma float_control(pop)

__global__ __launch_bounds__(256) void das_main(const float* __restrict__ data,
                                                const unsigned short* __restrict__ tab,
                                                const int* __restrict__ sxy,
                                                float* __restrict__ out) {
    __shared__ int sx[S_CNT];
    __shared__ int sy[S_CNT];
    int tid = threadIdx.x;
    if (tid < S_CNT) {
        sx[tid] = sxy[2 * tid];
        sy[tid] = sxy[2 * tid + 1];
    }
    __syncthreads();
    int iy = ((blockIdx.x & 31) << 4) | (tid & 15);
    int ix = ((blockIdx.x >> 5) << 4) | (tid >> 4);
    float acc[CH];
#pragma unroll
    for (int k = 0; k < CH; ++k) acc[k] = 0.0f;
#pragma unroll 4
    for (int s = 0; s < S_CNT; ++s) {
        int dxi = sx[s] - ix;
        int dyi = sy[s] - iy;
        int adx = dxi < 0 ? -dxi : dxi;
        int ady = dyi < 0 ? -dyi : dyi;
        int t = (int)tab[(adx << 9) | ady];
        const float* p = data + (s << 11) + t;
#pragma unroll
        for (int k = 0; k < CH; ++k) acc[k] += p[(size_t)k * CH_STRIDE];
    }
    int pix = (ix << 9) | iy;
#pragma unroll
    for (int k = 0; k < CH; ++k) out[k * NPIX + pix] = acc[k];
}

extern "C" void kernel_launch(void* const* d_in, const int* in_sizes, int n_in,
                              void* d_out, int out_size, void* d_ws, size_t ws_size,
                              hipStream_t stream) {
    const float* data = (const float*)d_in[0];     // (4,2,128,2048) f32
    const int* sxy = (const int*)d_in[1];          // (128,2) i32
    float* out = (float*)d_out;                    // (4,2,512,512) f32
    unsigned short* tab = (unsigned short*)d_ws;   // 512 KB

    size_t need = (size_t)TAB_BYTES + (size_t)CH_STRIDE * 16;  // 512KB + 4MB
    if (ws_size >= need) {
        uint4* d2b = (uint4*)((char*)d_ws + TAB_BYTES);
        prep4<<<NPIX / 1024, 256, 0, stream>>>(data, tab, d2b);
        das_hybrid<<<1024, 256, 0, stream>>>(d2b, tab, sxy, out);
    } else {
        build_table<<<NPIX / 256, 256, 0, stream>>>(tab);
        das_main<<<1024, 256, 0, stream>>>(data, tab, sxy, out);
    }
}